// Round 2
// baseline (391.172 us; speedup 1.0000x reference)
//
#include <hip/hip_runtime.h>

// Problem constants (fixed by the reference setup_inputs()).
#define N_NODES 100000
#define N_EDGES 1600000
#define IN_CH   128
#define HID_CH  64
#define OUT_CH  40
#define NBKT    196     // ceil(100000/512) buckets of 512 nodes
#define CAP     9216    // fixed bucket capacity (mean 8192, sigma ~90 -> 11 sigma)
#define NE4     (N_EDGES / 4)

using bf16x8 = __attribute__((ext_vector_type(8))) short;
using f32x4  = __attribute__((ext_vector_type(4))) float;

// bf16 helpers (tables are bf16; all accumulation fp32)
__device__ __forceinline__ float bf2f(unsigned short u) {
    union { unsigned int i; float f; } c; c.i = ((unsigned int)u) << 16; return c.f;
}
__device__ __forceinline__ unsigned short f2bf(float f) {
    union { float f; unsigned int i; } c; c.f = f;
    unsigned int r = c.i + 0x7FFFu + ((c.i >> 16) & 1u);  // RNE
    return (unsigned short)(r >> 16);
}
__device__ __forceinline__ float4 bf2f4(ushort4 u) {
    return make_float4(bf2f(u.x), bf2f(u.y), bf2f(u.z), bf2f(u.w));
}

// ---------------------------------------------------------------------------
// k_deg: edge-parallel in-degree count (fire-and-forget global atomics)
// NOTE: degree array is named `dgr` and addressed via pointer arithmetic —
// the literal token `%` + "deg" with ampersand gets HTML-entity-mangled in
// the submission transport.
// ---------------------------------------------------------------------------
__global__ void k_deg(const int* __restrict__ ei, int* __restrict__ dgr) {
    int i = blockIdx.x * blockDim.x + threadIdx.x;
    if (i >= NE4) return;
    const int4* D4 = (const int4*)(ei + N_EDGES);
    int4 d = D4[i];
    atomicAdd(dgr + d.x, 1);
    atomicAdd(dgr + d.y, 1);
    atomicAdd(dgr + d.z, 1);
    atomicAdd(dgr + d.w, 1);
}

// ---------------------------------------------------------------------------
// k_scan: per-bucket (512 nodes) exclusive scan of degrees with fixed base
// b*CAP. Emits row_start/row_end, placement cursor, dinv.
// ---------------------------------------------------------------------------
__global__ void k_scan(const int* __restrict__ dgr, int* __restrict__ row_start,
                       int* __restrict__ row_end, int* __restrict__ cursor,
                       float* __restrict__ dinv) {
    __shared__ int s[512];
    int tid = threadIdx.x, b = blockIdx.x;
    int node = (b << 9) + tid;
    int d = (node < N_NODES) ? dgr[node] : 0;
    s[tid] = d;
    __syncthreads();
#pragma unroll
    for (int off = 1; off < 512; off <<= 1) {
        int tv = (tid >= off) ? s[tid - off] : 0;
        __syncthreads();
        s[tid] += tv;
        __syncthreads();
    }
    if (node < N_NODES) {
        int start = b * CAP + s[tid] - d;
        row_start[node] = start;
        row_end[node]   = start + d;
        cursor[node]    = start;
        dinv[node]      = rsqrtf(1.0f + (float)d);
    }
}

// ---------------------------------------------------------------------------
// k_place: edge-parallel CSR placement via per-node cursors (returning
// atomics). Order within a node's list is nondeterministic — fp-benign.
// ---------------------------------------------------------------------------
__global__ void k_place(const int* __restrict__ ei, int* __restrict__ cursor,
                        int* __restrict__ csr_src) {
    int i = blockIdx.x * blockDim.x + threadIdx.x;
    if (i >= NE4) return;
    const int4* S4 = (const int4*)ei;
    const int4* D4 = (const int4*)(ei + N_EDGES);
    int4 s = S4[i];
    int4 d = D4[i];
    int p;
    p = atomicAdd(cursor + d.x, 1); csr_src[p] = s.x;
    p = atomicAdd(cursor + d.y, 1); csr_src[p] = s.y;
    p = atomicAdd(cursor + d.z, 1); csr_src[p] = s.z;
    p = atomicAdd(cursor + d.w, 1); csr_src[p] = s.w;
}

// ---------------------------------------------------------------------------
// GEMM1 (MFMA bf16): h1s[N,64] = bf16((x @ W1) * dinv[row])
// W1 transposed+converted during LDS staging (no prep kernel).
// ---------------------------------------------------------------------------
__global__ __launch_bounds__(256, 4)
void k_gemm1(const float* __restrict__ x, const float* __restrict__ W1,
             const float* __restrict__ dinv, unsigned short* __restrict__ h1s) {
    __shared__ unsigned short Al[64 * 136];  // 17 KB
    __shared__ unsigned short Bl[64 * 136];  // 17 KB
    __shared__ float dl[64];
    int tid = threadIdx.x;
    long long node0 = (long long)blockIdx.x * 64;

    const float4* X = (const float4*)x;    // row stride 32 f4
    for (int i = tid; i < 64 * 32; i += 256) {
        int r = i >> 5, c4 = i & 31;
        long long gr = node0 + r;
        if (gr >= N_NODES) gr = N_NODES - 1;
        float4 v = X[gr * 32 + c4];
        *(ushort4*)&Al[r * 136 + c4 * 4] =
            make_ushort4(f2bf(v.x), f2bf(v.y), f2bf(v.z), f2bf(v.w));
    }
    // stage B with transpose: W1[k][n] fp32 -> Bl[n*136 + k] bf16
    for (int i = tid; i < 128 * 64; i += 256) {
        int k = i >> 6, nn = i & 63;
        Bl[nn * 136 + k] = f2bf(W1[i]);
    }
    if (tid < 64) {
        long long gr = node0 + tid;
        dl[tid] = dinv[gr < N_NODES ? gr : N_NODES - 1];
    }
    __syncthreads();

    int lane = tid & 63, wave = tid >> 6;
    int quad = lane >> 4, l16 = lane & 15;
    int arow = wave * 16 + l16;
    f32x4 ac0 = {0,0,0,0}, ac1 = {0,0,0,0}, ac2 = {0,0,0,0}, ac3 = {0,0,0,0};

#pragma unroll
    for (int ks = 0; ks < 4; ++ks) {
        int ko = ks * 32 + quad * 8;
        bf16x8 a  = *(const bf16x8*)&Al[arow * 136 + ko];
        bf16x8 b0 = *(const bf16x8*)&Bl[( 0 + l16) * 136 + ko];
        bf16x8 b1 = *(const bf16x8*)&Bl[(16 + l16) * 136 + ko];
        bf16x8 b2 = *(const bf16x8*)&Bl[(32 + l16) * 136 + ko];
        bf16x8 b3 = *(const bf16x8*)&Bl[(48 + l16) * 136 + ko];
        ac0 = __builtin_amdgcn_mfma_f32_16x16x32_bf16(a, b0, ac0, 0, 0, 0);
        ac1 = __builtin_amdgcn_mfma_f32_16x16x32_bf16(a, b1, ac1, 0, 0, 0);
        ac2 = __builtin_amdgcn_mfma_f32_16x16x32_bf16(a, b2, ac2, 0, 0, 0);
        ac3 = __builtin_amdgcn_mfma_f32_16x16x32_bf16(a, b3, ac3, 0, 0, 0);
    }

#pragma unroll
    for (int r = 0; r < 4; ++r) {
        int rl = wave * 16 + quad * 4 + r;
        long long grow = node0 + rl;
        if (grow < N_NODES) {
            float dd = dl[rl];
            h1s[grow * 64 +  0 + l16] = f2bf(ac0[r] * dd);
            h1s[grow * 64 + 16 + l16] = f2bf(ac1[r] * dd);
            h1s[grow * 64 + 32 + l16] = f2bf(ac2[r] * dd);
            h1s[grow * 64 + 48 + l16] = f2bf(ac3[r] * dd);
        }
    }
}

// ---------------------------------------------------------------------------
// FUSED agg1 + gemm2: block owns 64 nodes.
// Phase B gather restructure: per 16-edge chunk, ONE coalesced index load
// (lane k loads csr_src[e+k], clamped), __shfl broadcast within the 16-lane
// group, then 16 independent gathers in flight; predicated accumulation into
// 4 accumulators. Critical path = 2 memory hops per chunk, no serial tail.
// Phase C: MFMA with W2 (transposed+padded to 48 cols during staging),
//   h2s[N,40] = bf16(tile @ W2 * dinv[row]).
// ---------------------------------------------------------------------------
__global__ __launch_bounds__(256, 4)
void k_agg1g2(const int* __restrict__ row_start, const int* __restrict__ row_end,
              const int* __restrict__ csr_src,
              const unsigned short* __restrict__ h1s, const float* __restrict__ dinv,
              const float* __restrict__ b1, const float* __restrict__ W2,
              unsigned short* __restrict__ h2s) {
    __shared__ unsigned short Al[64 * 72];  // 9 KB: relu'd layer-2 input tile
    __shared__ unsigned short Bl[48 * 72];  // 6.75 KB: W2^T bf16, n>=40 zero
    __shared__ float dl[64];
    int tid = threadIdx.x;
    long long node0 = (long long)blockIdx.x * 64;

    // stage W2^T (+pad) from fp32 [64][40]
    for (int i = tid; i < 48 * 64; i += 256) {
        int nn = i >> 6, k = i & 63;
        Bl[nn * 72 + k] = f2bf(nn < OUT_CH ? W2[k * OUT_CH + nn] : 0.0f);
    }
    if (tid < 64) {
        long long gr = node0 + tid;
        dl[tid] = dinv[gr < N_NODES ? gr : N_NODES - 1];
    }
    __syncthreads();   // dl needed below

    int cg = tid & 15;
    int nsub = tid >> 4;             // 0..15: node-within-round
    float4 bb = ((const float4*)b1)[cg];
    const ushort4* H = (const ushort4*)h1s;

#pragma unroll
    for (int r4 = 0; r4 < 4; ++r4) {
        int nl = r4 * 16 + nsub;                 // local row 0..63
        long long node = node0 + nl;
        ushort4 res = make_ushort4(0, 0, 0, 0);
        if (node < N_NODES) {
            int e = row_start[node];
            int nd = row_end[node] - e;          // remaining edges
            float4 a0 = bf2f4(H[node * 16 + cg]);   // self-loop
            float4 a1 = {0.f,0.f,0.f,0.f}, a2 = {0.f,0.f,0.f,0.f}, a3 = {0.f,0.f,0.f,0.f};
            while (nd > 0) {
                int kk = cg < nd ? cg : nd - 1;      // clamped: always valid
                int idxr = csr_src[e + kk];          // one coalesced load / chunk
                int K = nd < 16 ? nd : 16;
#define GSTEP(J, A) { int ss = __shfl(idxr, J, 16); \
                      ushort4 rw = H[(long long)ss * 16 + cg]; \
                      if (J < K) { float4 v = bf2f4(rw); \
                        A.x += v.x; A.y += v.y; A.z += v.z; A.w += v.w; } }
                GSTEP( 0, a0) GSTEP( 1, a1) GSTEP( 2, a2) GSTEP( 3, a3)
                GSTEP( 4, a0) GSTEP( 5, a1) GSTEP( 6, a2) GSTEP( 7, a3)
                GSTEP( 8, a0) GSTEP( 9, a1) GSTEP(10, a2) GSTEP(11, a3)
                GSTEP(12, a0) GSTEP(13, a1) GSTEP(14, a2) GSTEP(15, a3)
#undef GSTEP
                e += 16; nd -= 16;
            }
            a0.x += a1.x + a2.x + a3.x;
            a0.y += a1.y + a2.y + a3.y;
            a0.z += a1.z + a2.z + a3.z;
            a0.w += a1.w + a2.w + a3.w;
            float dd = dl[nl];
            res = make_ushort4(f2bf(fmaxf(a0.x * dd + bb.x, 0.f)),
                               f2bf(fmaxf(a0.y * dd + bb.y, 0.f)),
                               f2bf(fmaxf(a0.z * dd + bb.z, 0.f)),
                               f2bf(fmaxf(a0.w * dd + bb.w, 0.f)));
        }
        *(ushort4*)&Al[nl * 72 + cg * 4] = res;
    }
    __syncthreads();

    // Phase C: 64x48 MFMA tile (gemm2)
    int lane = tid & 63, wave = tid >> 6;
    int quad = lane >> 4, l16 = lane & 15;
    int arow = wave * 16 + l16;
    f32x4 ac0 = {0,0,0,0}, ac1 = {0,0,0,0}, ac2 = {0,0,0,0};

#pragma unroll
    for (int ks = 0; ks < 2; ++ks) {
        int ko = ks * 32 + quad * 8;
        bf16x8 a  = *(const bf16x8*)&Al[arow * 72 + ko];
        bf16x8 b0 = *(const bf16x8*)&Bl[( 0 + l16) * 72 + ko];
        bf16x8 b1v = *(const bf16x8*)&Bl[(16 + l16) * 72 + ko];
        bf16x8 b2 = *(const bf16x8*)&Bl[(32 + l16) * 72 + ko];
        ac0 = __builtin_amdgcn_mfma_f32_16x16x32_bf16(a, b0, ac0, 0, 0, 0);
        ac1 = __builtin_amdgcn_mfma_f32_16x16x32_bf16(a, b1v, ac1, 0, 0, 0);
        ac2 = __builtin_amdgcn_mfma_f32_16x16x32_bf16(a, b2, ac2, 0, 0, 0);
    }

#pragma unroll
    for (int r = 0; r < 4; ++r) {
        int rl = wave * 16 + quad * 4 + r;
        long long grow = node0 + rl;
        if (grow < N_NODES) {
            float dd = dl[rl];
            h2s[grow * 40 +  0 + l16] = f2bf(ac0[r] * dd);
            h2s[grow * 40 + 16 + l16] = f2bf(ac1[r] * dd);
            if (l16 < 8) h2s[grow * 40 + 32 + l16] = f2bf(ac2[r] * dd);
        }
    }
}

// ---------------------------------------------------------------------------
// CSR aggregation layer 2 (+bias): same chunked-ILP gather; lanes cg>=10
// still help load indices but skip the gather/accumulate.
// ---------------------------------------------------------------------------
__global__ __launch_bounds__(256, 4)
void k_agg2(const int* __restrict__ row_start, const int* __restrict__ row_end,
            const int* __restrict__ csr_src,
            const unsigned short* __restrict__ h2s, const float* __restrict__ dinv,
            const float* __restrict__ b2, float* __restrict__ out) {
    int idx = blockIdx.x * blockDim.x + threadIdx.x;
    int node = idx >> 4;
    int cg = idx & 15;
    if (node >= N_NODES) return;
    int e = row_start[node];
    int nd = row_end[node] - e;
    const ushort4* H = (const ushort4*)h2s;
    bool act = cg < 10;
    float4 a0 = {0.f,0.f,0.f,0.f}, a1 = a0, a2 = a0, a3 = a0;
    if (act) a0 = bf2f4(H[(long long)node * 10 + cg]);  // self-loop
    while (nd > 0) {
        int kk = cg < nd ? cg : nd - 1;
        int idxr = csr_src[e + kk];              // one coalesced load / chunk
        int K = nd < 16 ? nd : 16;
#define GSTEP2(J, A) { int ss = __shfl(idxr, J, 16); \
                       if (act && J < K) { \
                         float4 v = bf2f4(H[(long long)ss * 10 + cg]); \
                         A.x += v.x; A.y += v.y; A.z += v.z; A.w += v.w; } }
        GSTEP2( 0, a0) GSTEP2( 1, a1) GSTEP2( 2, a2) GSTEP2( 3, a3)
        GSTEP2( 4, a0) GSTEP2( 5, a1) GSTEP2( 6, a2) GSTEP2( 7, a3)
        GSTEP2( 8, a0) GSTEP2( 9, a1) GSTEP2(10, a2) GSTEP2(11, a3)
        GSTEP2(12, a0) GSTEP2(13, a1) GSTEP2(14, a2) GSTEP2(15, a3)
#undef GSTEP2
        e += 16; nd -= 16;
    }
    if (act) {
        a0.x += a1.x + a2.x + a3.x;
        a0.y += a1.y + a2.y + a3.y;
        a0.z += a1.z + a2.z + a3.z;
        a0.w += a1.w + a2.w + a3.w;
        float dd = dinv[node];
        float4 b = ((const float4*)b2)[cg];
        a0.x = a0.x * dd + b.x;
        a0.y = a0.y * dd + b.y;
        a0.z = a0.z * dd + b.z;
        a0.w = a0.w * dd + b.w;
        ((float4*)out)[(long long)node * 10 + cg] = a0;
    }
}

// ---------------------------------------------------------------------------
// launch
// ---------------------------------------------------------------------------
extern "C" void kernel_launch(void* const* d_in, const int* in_sizes, int n_in,
                              void* d_out, int out_size, void* d_ws, size_t ws_size,
                              hipStream_t stream) {
    const float* x  = (const float*)d_in[0];
    const int*   ei = (const int*)d_in[1];
    const float* W1 = (const float*)d_in[2];
    const float* b1 = (const float*)d_in[3];
    const float* W2 = (const float*)d_in[4];
    const float* b2 = (const float*)d_in[5];
    float* out = (float*)d_out;

    // workspace layout (16B-aligned regions), ~30 MB:
    // hbuf bf16[64N] (h1s) | h2buf bf16[40N] (h2s) |
    // csr_src[NBKT*CAP] | row_start[N] | row_end[N] | cursor[N] | dgr[N] | dinv[N]
    unsigned short* hbuf  = (unsigned short*)d_ws;                // 64N bf16
    unsigned short* h2buf = hbuf + 64LL * N_NODES;                // 40N bf16
    int* csr_src   = (int*)(h2buf + 40LL * N_NODES);              // NBKT*CAP
    int* row_start = csr_src + NBKT * CAP;                        // N
    int* row_end   = row_start + N_NODES;                         // N
    int* cursor    = row_end + N_NODES;                           // N
    int* dgr       = cursor + N_NODES;                            // N
    float* dinv    = (float*)(dgr + N_NODES);                     // N

    const int B = 256;
    const int gE   = (NE4 + B - 1) / B;           // 1563 (edge-parallel)
    const int g16  = (N_NODES * 16 + B - 1) / B;  // 6250
    const int gRows = (N_NODES + 63) / 64;        // 1563

    hipMemsetAsync((void*)dgr, 0, N_NODES * sizeof(int), stream);
    k_deg<<<gE, B, 0, stream>>>(ei, dgr);
    k_scan<<<NBKT, 512, 0, stream>>>(dgr, row_start, row_end, cursor, dinv);
    k_place<<<gE, B, 0, stream>>>(ei, cursor, csr_src);

    k_gemm1<<<gRows, B, 0, stream>>>(x, W1, dinv, hbuf);
    k_agg1g2<<<gRows, B, 0, stream>>>(row_start, row_end, csr_src, hbuf, dinv,
                                      b1, W2, h2buf);
    k_agg2<<<g16, B, 0, stream>>>(row_start, row_end, csr_src, h2buf, dinv, b2, out);
}

// Round 3
// 236.587 us; speedup vs baseline: 1.6534x; 1.6534x over previous
//
#include <hip/hip_runtime.h>

// Problem constants (fixed by the reference setup_inputs()).
#define N_NODES 100000
#define N_EDGES 1600000
#define IN_CH   128
#define HID_CH  64
#define OUT_CH  40
#define NBKT    196     // ceil(100000/512) buckets of 512 nodes
#define EPB     4096    // edges per k_bin block
#define CAP     9216    // fixed bucket capacity (mean 8186, sigma ~90 -> 11 sigma)

using bf16x8 = __attribute__((ext_vector_type(8))) short;
using f32x4  = __attribute__((ext_vector_type(4))) float;

// bf16 helpers (tables are bf16; all accumulation fp32)
__device__ __forceinline__ float bf2f(unsigned short u) {
    union { unsigned int i; float f; } c; c.i = ((unsigned int)u) << 16; return c.f;
}
__device__ __forceinline__ unsigned short f2bf(float f) {
    union { float f; unsigned int i; } c; c.f = f;
    unsigned int r = c.i + 0x7FFFu + ((c.i >> 16) & 1u);  // RNE
    return (unsigned short)(r >> 16);
}
__device__ __forceinline__ float4 bf2f4(ushort4 u) {
    return make_float4(bf2f(u.x), bf2f(u.y), bf2f(u.z), bf2f(u.w));
}

// ---------------------------------------------------------------------------
// bin edges into fixed-base bucket regions; gcur holds per-bucket DELTAS
// (zeroed by hipMemsetAsync). packed word: src | ((dst&511)<<17)
// (proven round-0 path: LDS histograms -> 196 global atomics/block; avoids
// the cross-XCD cursor-atomic + scattered-write disaster of edge-parallel
// placement: that variant showed WRITE_SIZE 108MB and 121us.)
// ---------------------------------------------------------------------------
__global__ void k_bin(const int* __restrict__ ei, int* __restrict__ gcur,
                      int* __restrict__ ebuf) {
    __shared__ int hist[NBKT];
    __shared__ int lcur[NBKT];
    int tid = threadIdx.x;
    int base = blockIdx.x * EPB;
    int nloc = N_EDGES - base;
    if (nloc > EPB) nloc = EPB;
    int n4 = nloc >> 2;   // nloc is 4096 or 2560, both %4==0
    const int4* S4 = (const int4*)(ei + base);
    const int4* D4 = (const int4*)(ei + N_EDGES + base);

    if (tid < NBKT) { hist[tid] = 0; }
    __syncthreads();
    for (int i = tid; i < n4; i += 256) {
        int4 d = D4[i];
        atomicAdd(&hist[d.x >> 9], 1);
        atomicAdd(&hist[d.y >> 9], 1);
        atomicAdd(&hist[d.z >> 9], 1);
        atomicAdd(&hist[d.w >> 9], 1);
    }
    __syncthreads();
    if (tid < NBKT) {
        int h = hist[tid];
        lcur[tid] = h ? (tid * CAP + atomicAdd(&gcur[tid], h)) : 0;
    }
    __syncthreads();
    for (int i = tid; i < n4; i += 256) {
        int4 s = S4[i];
        int4 d = D4[i];
        int p;
        p = atomicAdd(&lcur[d.x >> 9], 1); ebuf[p] = s.x | ((d.x & 511) << 17);
        p = atomicAdd(&lcur[d.y >> 9], 1); ebuf[p] = s.y | ((d.y & 511) << 17);
        p = atomicAdd(&lcur[d.z >> 9], 1); ebuf[p] = s.z | ((d.z & 511) << 17);
        p = atomicAdd(&lcur[d.w >> 9], 1); ebuf[p] = s.w | ((d.w & 511) << 17);
    }
}

// ---------------------------------------------------------------------------
// per-bucket (512 nodes, 512 threads): count nodes in LDS, scan, emit
// row_start/row_end/dinv, place edges into exact per-node CSR order.
// ---------------------------------------------------------------------------
__global__ void k_node(const int* __restrict__ gcur, const int* __restrict__ ebuf,
                       int* __restrict__ row_start, int* __restrict__ row_end,
                       int* __restrict__ csr_src, float* __restrict__ dinv) {
    __shared__ int cnt[512];
    __shared__ int s[512];
    int tid = threadIdx.x;
    int b = blockIdx.x;
    int node0 = b << 9;
    int lo = b * CAP;
    int hi = lo + gcur[b];
    int n = hi - lo, n4 = n >> 2;
    const int4* E4 = (const int4*)(ebuf + lo);   // lo*4B = b*36KB, 16B aligned

    cnt[tid] = 0;
    __syncthreads();
    for (int i = tid; i < n4; i += 512) {
        int4 w = E4[i];
        atomicAdd(&cnt[(unsigned)w.x >> 17], 1);
        atomicAdd(&cnt[(unsigned)w.y >> 17], 1);
        atomicAdd(&cnt[(unsigned)w.z >> 17], 1);
        atomicAdd(&cnt[(unsigned)w.w >> 17], 1);
    }
    for (int e = lo + (n4 << 2) + tid; e < hi; e += 512)
        atomicAdd(&cnt[(unsigned)ebuf[e] >> 17], 1);
    __syncthreads();
    int c = cnt[tid];
    s[tid] = c;
    __syncthreads();
#pragma unroll
    for (int off = 1; off < 512; off <<= 1) {
        int tv = (tid >= off) ? s[tid - off] : 0;
        __syncthreads();
        s[tid] += tv;
        __syncthreads();
    }
    int node = node0 + tid;
    if (node < N_NODES) {
        row_start[node] = lo + s[tid] - c;
        row_end[node]   = lo + s[tid];
        dinv[node] = rsqrtf(1.0f + (float)c);
    }
    __syncthreads();
    cnt[tid] = lo + s[tid] - c;  // reuse as cursor
    __syncthreads();
    for (int i = tid; i < n4; i += 512) {
        int4 w = E4[i];
        int p;
        p = atomicAdd(&cnt[(unsigned)w.x >> 17], 1); csr_src[p] = w.x & 0x1FFFF;
        p = atomicAdd(&cnt[(unsigned)w.y >> 17], 1); csr_src[p] = w.y & 0x1FFFF;
        p = atomicAdd(&cnt[(unsigned)w.z >> 17], 1); csr_src[p] = w.z & 0x1FFFF;
        p = atomicAdd(&cnt[(unsigned)w.w >> 17], 1); csr_src[p] = w.w & 0x1FFFF;
    }
    for (int e = lo + (n4 << 2) + tid; e < hi; e += 512) {
        int w = ebuf[e];
        int p = atomicAdd(&cnt[(unsigned)w >> 17], 1);
        csr_src[p] = w & 0x1FFFF;
    }
}

// ---------------------------------------------------------------------------
// GEMM1 (MFMA bf16): h1s[N,64] = bf16((x @ W1) * dinv[row])
// W1 transposed+converted during LDS staging (no prep kernel).
// ---------------------------------------------------------------------------
__global__ __launch_bounds__(256, 4)
void k_gemm1(const float* __restrict__ x, const float* __restrict__ W1,
             const float* __restrict__ dinv, unsigned short* __restrict__ h1s) {
    __shared__ unsigned short Al[64 * 136];  // 17 KB
    __shared__ unsigned short Bl[64 * 136];  // 17 KB
    __shared__ float dl[64];
    int tid = threadIdx.x;
    long long node0 = (long long)blockIdx.x * 64;

    const float4* X = (const float4*)x;    // row stride 32 f4
    for (int i = tid; i < 64 * 32; i += 256) {
        int r = i >> 5, c4 = i & 31;
        long long gr = node0 + r;
        if (gr >= N_NODES) gr = N_NODES - 1;
        float4 v = X[gr * 32 + c4];
        *(ushort4*)&Al[r * 136 + c4 * 4] =
            make_ushort4(f2bf(v.x), f2bf(v.y), f2bf(v.z), f2bf(v.w));
    }
    // stage B with transpose: W1[k][n] fp32 -> Bl[n*136 + k] bf16
    for (int i = tid; i < 128 * 64; i += 256) {
        int k = i >> 6, nn = i & 63;
        Bl[nn * 136 + k] = f2bf(W1[i]);
    }
    if (tid < 64) {
        long long gr = node0 + tid;
        dl[tid] = dinv[gr < N_NODES ? gr : N_NODES - 1];
    }
    __syncthreads();

    int lane = tid & 63, wave = tid >> 6;
    int quad = lane >> 4, l16 = lane & 15;
    int arow = wave * 16 + l16;
    f32x4 ac0 = {0,0,0,0}, ac1 = {0,0,0,0}, ac2 = {0,0,0,0}, ac3 = {0,0,0,0};

#pragma unroll
    for (int ks = 0; ks < 4; ++ks) {
        int ko = ks * 32 + quad * 8;
        bf16x8 a  = *(const bf16x8*)&Al[arow * 136 + ko];
        bf16x8 b0 = *(const bf16x8*)&Bl[( 0 + l16) * 136 + ko];
        bf16x8 b1 = *(const bf16x8*)&Bl[(16 + l16) * 136 + ko];
        bf16x8 b2 = *(const bf16x8*)&Bl[(32 + l16) * 136 + ko];
        bf16x8 b3 = *(const bf16x8*)&Bl[(48 + l16) * 136 + ko];
        ac0 = __builtin_amdgcn_mfma_f32_16x16x32_bf16(a, b0, ac0, 0, 0, 0);
        ac1 = __builtin_amdgcn_mfma_f32_16x16x32_bf16(a, b1, ac1, 0, 0, 0);
        ac2 = __builtin_amdgcn_mfma_f32_16x16x32_bf16(a, b2, ac2, 0, 0, 0);
        ac3 = __builtin_amdgcn_mfma_f32_16x16x32_bf16(a, b3, ac3, 0, 0, 0);
    }

#pragma unroll
    for (int r = 0; r < 4; ++r) {
        int rl = wave * 16 + quad * 4 + r;
        long long grow = node0 + rl;
        if (grow < N_NODES) {
            float dd = dl[rl];
            h1s[grow * 64 +  0 + l16] = f2bf(ac0[r] * dd);
            h1s[grow * 64 + 16 + l16] = f2bf(ac1[r] * dd);
            h1s[grow * 64 + 32 + l16] = f2bf(ac2[r] * dd);
            h1s[grow * 64 + 48 + l16] = f2bf(ac3[r] * dd);
        }
    }
}

// ---------------------------------------------------------------------------
// FUSED agg1 + gemm2: block owns 64 nodes.
// Phase B gather: per 16-edge chunk, ONE coalesced index load (lane k loads
// csr_src[e+k], clamped), __shfl broadcast within the 16-lane group, then 16
// independent gathers in flight; predicated accumulation into 4 accumulators.
// Critical path = 2 memory hops per chunk, no serial tail.
// Phase C: MFMA with W2 (transposed+padded to 48 cols during staging),
//   h2s[N,40] = bf16(tile @ W2 * dinv[row]).
// ---------------------------------------------------------------------------
__global__ __launch_bounds__(256, 4)
void k_agg1g2(const int* __restrict__ row_start, const int* __restrict__ row_end,
              const int* __restrict__ csr_src,
              const unsigned short* __restrict__ h1s, const float* __restrict__ dinv,
              const float* __restrict__ b1, const float* __restrict__ W2,
              unsigned short* __restrict__ h2s) {
    __shared__ unsigned short Al[64 * 72];  // 9 KB: relu'd layer-2 input tile
    __shared__ unsigned short Bl[48 * 72];  // 6.75 KB: W2^T bf16, n>=40 zero
    __shared__ float dl[64];
    int tid = threadIdx.x;
    long long node0 = (long long)blockIdx.x * 64;

    // stage W2^T (+pad) from fp32 [64][40]
    for (int i = tid; i < 48 * 64; i += 256) {
        int nn = i >> 6, k = i & 63;
        Bl[nn * 72 + k] = f2bf(nn < OUT_CH ? W2[k * OUT_CH + nn] : 0.0f);
    }
    if (tid < 64) {
        long long gr = node0 + tid;
        dl[tid] = dinv[gr < N_NODES ? gr : N_NODES - 1];
    }
    __syncthreads();   // dl needed below

    int cg = tid & 15;
    int nsub = tid >> 4;             // 0..15: node-within-round
    float4 bb = ((const float4*)b1)[cg];
    const ushort4* H = (const ushort4*)h1s;

#pragma unroll
    for (int r4 = 0; r4 < 4; ++r4) {
        int nl = r4 * 16 + nsub;                 // local row 0..63
        long long node = node0 + nl;
        ushort4 res = make_ushort4(0, 0, 0, 0);
        if (node < N_NODES) {
            int e = row_start[node];
            int nd = row_end[node] - e;          // remaining edges
            float4 a0 = bf2f4(H[node * 16 + cg]);   // self-loop
            float4 a1 = {0.f,0.f,0.f,0.f}, a2 = {0.f,0.f,0.f,0.f}, a3 = {0.f,0.f,0.f,0.f};
            while (nd > 0) {
                int kk = cg < nd ? cg : nd - 1;      // clamped: always valid
                int idxr = csr_src[e + kk];          // one coalesced load / chunk
                int K = nd < 16 ? nd : 16;
#define GSTEP(J, A) { int ss = __shfl(idxr, J, 16); \
                      ushort4 rw = H[(long long)ss * 16 + cg]; \
                      if (J < K) { float4 v = bf2f4(rw); \
                        A.x += v.x; A.y += v.y; A.z += v.z; A.w += v.w; } }
                GSTEP( 0, a0) GSTEP( 1, a1) GSTEP( 2, a2) GSTEP( 3, a3)
                GSTEP( 4, a0) GSTEP( 5, a1) GSTEP( 6, a2) GSTEP( 7, a3)
                GSTEP( 8, a0) GSTEP( 9, a1) GSTEP(10, a2) GSTEP(11, a3)
                GSTEP(12, a0) GSTEP(13, a1) GSTEP(14, a2) GSTEP(15, a3)
#undef GSTEP
                e += 16; nd -= 16;
            }
            a0.x += a1.x + a2.x + a3.x;
            a0.y += a1.y + a2.y + a3.y;
            a0.z += a1.z + a2.z + a3.z;
            a0.w += a1.w + a2.w + a3.w;
            float dd = dl[nl];
            res = make_ushort4(f2bf(fmaxf(a0.x * dd + bb.x, 0.f)),
                               f2bf(fmaxf(a0.y * dd + bb.y, 0.f)),
                               f2bf(fmaxf(a0.z * dd + bb.z, 0.f)),
                               f2bf(fmaxf(a0.w * dd + bb.w, 0.f)));
        }
        *(ushort4*)&Al[nl * 72 + cg * 4] = res;
    }
    __syncthreads();

    // Phase C: 64x48 MFMA tile (gemm2)
    int lane = tid & 63, wave = tid >> 6;
    int quad = lane >> 4, l16 = lane & 15;
    int arow = wave * 16 + l16;
    f32x4 ac0 = {0,0,0,0}, ac1 = {0,0,0,0}, ac2 = {0,0,0,0};

#pragma unroll
    for (int ks = 0; ks < 2; ++ks) {
        int ko = ks * 32 + quad * 8;
        bf16x8 a  = *(const bf16x8*)&Al[arow * 72 + ko];
        bf16x8 b0 = *(const bf16x8*)&Bl[( 0 + l16) * 72 + ko];
        bf16x8 b1v = *(const bf16x8*)&Bl[(16 + l16) * 72 + ko];
        bf16x8 b2 = *(const bf16x8*)&Bl[(32 + l16) * 72 + ko];
        ac0 = __builtin_amdgcn_mfma_f32_16x16x32_bf16(a, b0, ac0, 0, 0, 0);
        ac1 = __builtin_amdgcn_mfma_f32_16x16x32_bf16(a, b1v, ac1, 0, 0, 0);
        ac2 = __builtin_amdgcn_mfma_f32_16x16x32_bf16(a, b2, ac2, 0, 0, 0);
    }

#pragma unroll
    for (int r = 0; r < 4; ++r) {
        int rl = wave * 16 + quad * 4 + r;
        long long grow = node0 + rl;
        if (grow < N_NODES) {
            float dd = dl[rl];
            h2s[grow * 40 +  0 + l16] = f2bf(ac0[r] * dd);
            h2s[grow * 40 + 16 + l16] = f2bf(ac1[r] * dd);
            if (l16 < 8) h2s[grow * 40 + 32 + l16] = f2bf(ac2[r] * dd);
        }
    }
}

// ---------------------------------------------------------------------------
// CSR aggregation layer 2 (+bias): same chunked-ILP gather; lanes cg>=10
// help load indices but skip the gather/accumulate.
// ---------------------------------------------------------------------------
__global__ __launch_bounds__(256, 4)
void k_agg2(const int* __restrict__ row_start, const int* __restrict__ row_end,
            const int* __restrict__ csr_src,
            const unsigned short* __restrict__ h2s, const float* __restrict__ dinv,
            const float* __restrict__ b2, float* __restrict__ out) {
    int idx = blockIdx.x * blockDim.x + threadIdx.x;
    int node = idx >> 4;
    int cg = idx & 15;
    if (node >= N_NODES) return;
    int e = row_start[node];
    int nd = row_end[node] - e;
    const ushort4* H = (const ushort4*)h2s;
    bool act = cg < 10;
    float4 a0 = {0.f,0.f,0.f,0.f}, a1 = a0, a2 = a0, a3 = a0;
    if (act) a0 = bf2f4(H[(long long)node * 10 + cg]);  // self-loop
    while (nd > 0) {
        int kk = cg < nd ? cg : nd - 1;
        int idxr = csr_src[e + kk];              // one coalesced load / chunk
        int K = nd < 16 ? nd : 16;
#define GSTEP2(J, A) { int ss = __shfl(idxr, J, 16); \
                       if (act && J < K) { \
                         float4 v = bf2f4(H[(long long)ss * 10 + cg]); \
                         A.x += v.x; A.y += v.y; A.z += v.z; A.w += v.w; } }
        GSTEP2( 0, a0) GSTEP2( 1, a1) GSTEP2( 2, a2) GSTEP2( 3, a3)
        GSTEP2( 4, a0) GSTEP2( 5, a1) GSTEP2( 6, a2) GSTEP2( 7, a3)
        GSTEP2( 8, a0) GSTEP2( 9, a1) GSTEP2(10, a2) GSTEP2(11, a3)
        GSTEP2(12, a0) GSTEP2(13, a1) GSTEP2(14, a2) GSTEP2(15, a3)
#undef GSTEP2
        e += 16; nd -= 16;
    }
    if (act) {
        a0.x += a1.x + a2.x + a3.x;
        a0.y += a1.y + a2.y + a3.y;
        a0.z += a1.z + a2.z + a3.z;
        a0.w += a1.w + a2.w + a3.w;
        float dd = dinv[node];
        float4 b = ((const float4*)b2)[cg];
        a0.x = a0.x * dd + b.x;
        a0.y = a0.y * dd + b.y;
        a0.z = a0.z * dd + b.z;
        a0.w = a0.w * dd + b.w;
        ((float4*)out)[(long long)node * 10 + cg] = a0;
    }
}

// ---------------------------------------------------------------------------
// launch
// ---------------------------------------------------------------------------
extern "C" void kernel_launch(void* const* d_in, const int* in_sizes, int n_in,
                              void* d_out, int out_size, void* d_ws, size_t ws_size,
                              hipStream_t stream) {
    const float* x  = (const float*)d_in[0];
    const int*   ei = (const int*)d_in[1];
    const float* W1 = (const float*)d_in[2];
    const float* b1 = (const float*)d_in[3];
    const float* W2 = (const float*)d_in[4];
    const float* b2 = (const float*)d_in[5];
    float* out = (float*)d_out;

    // workspace layout (16B-aligned regions), ~41 MB:
    // hbuf bf16[64N] (h1s) | h2buf bf16[64N] (h2s, 40N used) |
    // ebuf[NBKT*CAP] | csr_src[NBKT*CAP] | row_start[N] | row_end[N] |
    // gcur[256] | dinv[N]
    unsigned short* hbuf  = (unsigned short*)d_ws;                // 64N bf16
    unsigned short* h2buf = hbuf + 64LL * N_NODES;                // 64N bf16
    int* ebuf      = (int*)(h2buf + 64LL * N_NODES);              // NBKT*CAP
    int* csr_src   = ebuf + NBKT * CAP;                           // NBKT*CAP
    int* row_start = csr_src + NBKT * CAP;                        // N
    int* row_end   = row_start + N_NODES;                         // N
    int* gcur      = row_end + N_NODES;                           // 256
    float* dinv    = (float*)(gcur + 256);                        // N

    const int B = 256;
    const int g16 = (N_NODES * 16 + B - 1) / B;   // 6250
    const int gRows = (N_NODES + 63) / 64;        // 1563

    hipMemsetAsync((void*)gcur, 0, NBKT * sizeof(int), stream);
    k_bin<<<(N_EDGES + EPB - 1) / EPB, B, 0, stream>>>(ei, gcur, ebuf);
    k_node<<<NBKT, 512, 0, stream>>>(gcur, ebuf, row_start, row_end, csr_src, dinv);

    k_gemm1<<<gRows, B, 0, stream>>>(x, W1, dinv, hbuf);
    k_agg1g2<<<gRows, B, 0, stream>>>(row_start, row_end, csr_src, hbuf, dinv,
                                      b1, W2, h2buf);
    k_agg2<<<g16, B, 0, stream>>>(row_start, row_end, csr_src, h2buf, dinv, b2, out);
}